// Round 9
// baseline (827.721 us; speedup 1.0000x reference)
//
#include <hip/hip_runtime.h>
#include <math.h>

#define NPTS 4096
#define MPTS 4096
#define NSTEPS 8
#define ICP_TOL 1e-6f
#define NBLK 1024   // 4 blocks/CU; residency guaranteed by __launch_bounds__(256,4)
#define NSLOT 32    // accumulator striping slots per batch
#define NSUB 32     // barrier arrival sub-counters (32 blocks each)

// ws layout (floats):
//   ptgt4 : [0, 32768)        interleaved {x,y,z,0.5*|t|^2} for 2*4096 targets
//   acc   : [32768, 40960)    [step][batch][slot(32)][16] striped partial sums
//   ctrs  : words at float off 40960, stride 1536/step:
//             sub-counters at c*16 (c<32), master at 512, flags at 1024+f*16 (f<32)
#define ACC_OFF 32768
#define CTR_OFF 40960
#define CTR_STRIDE 1536

__global__ void init_kernel(const float* __restrict__ ptgt, float* __restrict__ ws) {
    float* ptgt4 = ws;
    float* acc = ws + ACC_OFF;
    unsigned* ctrs = (unsigned*)(ws + CTR_OFF);
    int gid = blockIdx.x * 256 + threadIdx.x;   // 8192 threads
    if (gid < 2 * MPTS) {
        float x = ptgt[3 * gid + 0];
        float y = ptgt[3 * gid + 1];
        float z = ptgt[3 * gid + 2];
        float4 v;
        v.x = x; v.y = y; v.z = z;
        v.w = 0.5f * (x * x + y * y + z * z);
        ((float4*)ptgt4)[gid] = v;
    }
    if (gid < NSTEPS * 2 * NSLOT * 16) acc[gid] = 0.f;   // 8192 floats
    for (int i = gid; i < NSTEPS * CTR_STRIDE; i += 8192) ctrs[i] = 0u;
}

// Fence-free two-level grid barrier, striped release flags (proven R7/R8:
// agent-scope atomics are cross-XCD coherent without fences; ordering via
// __syncthreads vmcnt(0) drain -> arrival RMW chain -> flag stores).
__device__ __forceinline__ void grid_barrier(unsigned* stepc, int bid) {
    __syncthreads();
    if (threadIdx.x == 0) {
        unsigned* sub = stepc + (bid & (NSUB - 1)) * 16;
        unsigned old = __hip_atomic_fetch_add(sub, 1u, __ATOMIC_RELAXED,
                                              __HIP_MEMORY_SCOPE_AGENT);
        if (old == (unsigned)(NBLK / NSUB) - 1u) {
            unsigned o2 = __hip_atomic_fetch_add(stepc + 512, 1u, __ATOMIC_RELAXED,
                                                 __HIP_MEMORY_SCOPE_AGENT);
            if (o2 == (unsigned)NSUB - 1u) {
#pragma unroll
                for (int f = 0; f < 32; ++f)
                    __hip_atomic_store(stepc + 1024 + f * 16, 1u,
                                       __ATOMIC_RELAXED, __HIP_MEMORY_SCOPE_AGENT);
            }
        }
        unsigned* myflag = stepc + 1024 + (bid & 31) * 16;
        while (__hip_atomic_load(myflag, __ATOMIC_RELAXED,
                                 __HIP_MEMORY_SCOPE_AGENT) == 0u) {
            __builtin_amdgcn_s_sleep(2);
        }
    }
    __syncthreads();
    __asm__ volatile("" ::: "memory");
}

__device__ __forceinline__ float frcp(float x) {
#if __has_builtin(__builtin_amdgcn_rcpf)
    return __builtin_amdgcn_rcpf(x);
#else
    return 1.f / x;
#endif
}
__device__ __forceinline__ float frsq(float x) {
#if __has_builtin(__builtin_amdgcn_rsqf)
    return __builtin_amdgcn_rsqf(x);
#else
    return 1.f / sqrtf(x);
#endif
}

__device__ __forceinline__ void jacobi4(float A[4][4], float V[4][4]) {
    for (int i = 0; i < 4; ++i)
        for (int j = 0; j < 4; ++j) V[i][j] = (i == j) ? 1.f : 0.f;
    for (int sweep = 0; sweep < 5; ++sweep) {
        float diag = fabsf(A[0][0]) + fabsf(A[1][1]) + fabsf(A[2][2]) + fabsf(A[3][3]);
        float off = fabsf(A[0][1]) + fabsf(A[0][2]) + fabsf(A[0][3])
                  + fabsf(A[1][2]) + fabsf(A[1][3]) + fabsf(A[2][3]);
        if (off < 1e-6f * diag) break;
        for (int p = 0; p < 3; ++p) {
            for (int q = p + 1; q < 4; ++q) {
                float apq = A[p][q];
                if (fabsf(apq) < 1e-30f) continue;
                float theta = (A[q][q] - A[p][p]) * 0.5f * frcp(apq);
                float t = frcp(fabsf(theta) + sqrtf(theta * theta + 1.f));
                if (theta < 0.f) t = -t;
                float c = frsq(t * t + 1.f);
                float s = t * c;
                for (int k = 0; k < 4; ++k) {
                    float akp = A[k][p], akq = A[k][q];
                    A[k][p] = c * akp - s * akq;
                    A[k][q] = s * akp + c * akq;
                }
                for (int k = 0; k < 4; ++k) {
                    float apk = A[p][k], aqk = A[q][k];
                    A[p][k] = c * apk - s * aqk;
                    A[q][k] = s * apk + c * aqk;
                }
                for (int k = 0; k < 4; ++k) {
                    float vkp = V[k][p], vkq = V[k][q];
                    V[k][p] = c * vkp - s * vkq;
                    V[k][q] = s * vkp + c * vkq;
                }
            }
        }
    }
}

#define FOR8(OP) OP(0) OP(1) OP(2) OP(3) OP(4) OP(5) OP(6) OP(7)

// 1024 blocks x 256 threads, persistent (4 blocks/CU -> double the TLP of R8;
// NN loop is latency-bound, R4->R5 showed time ~ 1/occupancy). Block handles
// 8 source points of batch b = bid>>9 (named scalars); wave w scans target
// slice [w*1024,(w+1)*1024), one float4 target per lane per iter, prefetch
// depth 4. Per step: NN -> striped RMW atomics -> fence-free barrier ->
// 32-slot gather -> redundant per-block 4x4 Kabsch (bit-identical).
__global__ __launch_bounds__(256, 4) void icp_main(
    const float* __restrict__ psrc, float* __restrict__ ws,
    float* __restrict__ out) {

    float* ptgt4 = ws;
    float* acc = ws + ACC_OFF;
    unsigned* ctrs = (unsigned*)(ws + CTR_OFF);

    __shared__ float st[2][13];
    __shared__ unsigned keys[4][8];
    __shared__ float red[8][16];
    __shared__ float asum[2][16];
    __shared__ float convs[2];

    const int tid = threadIdx.x;
    const int bid = blockIdx.x;
    const int b = bid >> 9;            // batch (512 blocks each)
    const int n0 = (bid & 511) * 8;    // this block's 8 source points

    if (tid < 2) {
        st[tid][0] = 1.f; st[tid][1] = 0.f; st[tid][2] = 0.f;
        st[tid][3] = 0.f; st[tid][4] = 1.f; st[tid][5] = 0.f;
        st[tid][6] = 0.f; st[tid][7] = 0.f; st[tid][8] = 1.f;
        st[tid][9] = 0.f; st[tid][10] = 0.f; st[tid][11] = 0.f;
        st[tid][12] = 0.f;
    }
    __syncthreads();

    const int w = tid >> 6, lane = tid & 63;
    const int m0 = w * 1024 + lane;
    const float4* tpb = (const float4*)ptgt4 + ((size_t)b * MPTS + m0);
    const float* ps = psrc + ((size_t)b * NPTS + n0) * 3;

    for (int step = 0; step < NSTEPS; ++step) {
        float R00 = st[b][0], R01 = st[b][1], R02 = st[b][2];
        float R10 = st[b][3], R11 = st[b][4], R12 = st[b][5];
        float R20 = st[b][6], R21 = st[b][7], R22 = st[b][8];
        float t0 = st[b][9], t1 = st[b][10], t2 = st[b][11];

#define DECLP(i) float px##i, py##i, pz##i;
        FOR8(DECLP)
#undef DECLP
#define LOADP(i) { float x = ps[3*(i)], y = ps[3*(i)+1], z = ps[3*(i)+2]; \
        px##i = fmaf(R00, x, fmaf(R01, y, fmaf(R02, z, t0))); \
        py##i = fmaf(R10, x, fmaf(R11, y, fmaf(R12, z, t1))); \
        pz##i = fmaf(R20, x, fmaf(R21, y, fmaf(R22, z, t2))); }
        FOR8(LOADP)
#undef LOADP

        // s = p.t - |t|^2/2; argmax s == argmin dist (strict > keeps first max)
#define DECLB(i) float bs##i = -3.0e38f; int ix##i = m0;
        FOR8(DECLB)
#undef DECLB

        float4 tc0 = tpb[0];
        float4 tc1 = tpb[64];
        float4 tc2 = tpb[128];
        float4 tc3 = tpb[192];
        int mreg = m0;
#pragma unroll
        for (int k = 0; k < 16; ++k) {
            float4 tnx = tpb[((k + 4) & 15) * 64];  // prefetch depth 4 (wraps)
            float tx = tc0.x, ty = tc0.y, tz = tc0.z, htn = tc0.w;
#define PAIR(i) { float s = fmaf(px##i, tx, fmaf(py##i, ty, fmaf(pz##i, tz, -htn))); \
            if (s > bs##i) { bs##i = s; ix##i = mreg; } }
            FOR8(PAIR)
#undef PAIR
            mreg += 64;
            tc0 = tc1; tc1 = tc2; tc2 = tc3; tc3 = tnx;
        }

        // wave argmax via order-preserving packed key: score hi-20 | (4095-m)
#define REDKEY(i) { unsigned ub = __float_as_uint(bs##i); \
        unsigned u = ((int)ub >= 0) ? (ub | 0x80000000u) : ~ub; \
        unsigned key = (u & 0xFFFFF000u) | (4095u - (unsigned)ix##i); \
        for (int off = 32; off; off >>= 1) { \
            unsigned o = (unsigned)__shfl_xor((int)key, off); \
            key = key > o ? key : o; } \
        if (lane == 0) keys[w][i] = key; }
        FOR8(REDKEY)
#undef REDKEY
        __syncthreads();

        if (tid < 8) {
            unsigned key = keys[0][tid];
            unsigned k1 = keys[1][tid], k2 = keys[2][tid], k3 = keys[3][tid];
            key = key > k1 ? key : k1;
            key = key > k2 ? key : k2;
            key = key > k3 ? key : k3;
            int m = 4095 - (int)(key & 0xFFFu);
            float4 q = ((const float4*)ptgt4)[(size_t)b * MPTS + m];
            const float* pp = psrc + ((size_t)b * NPTS + n0 + tid) * 3;
            float x = pp[0], y = pp[1], z = pp[2];
            float px = fmaf(R00, x, fmaf(R01, y, fmaf(R02, z, t0)));
            float py = fmaf(R10, x, fmaf(R11, y, fmaf(R12, z, t1)));
            float pz = fmaf(R20, x, fmaf(R21, y, fmaf(R22, z, t2)));
            float dx = px - q.x, dy = py - q.y, dz = pz - q.z;
            float dist = sqrtf(dx * dx + dy * dy + dz * dz);
            red[tid][0] = px; red[tid][1] = py; red[tid][2] = pz;
            red[tid][3] = q.x; red[tid][4] = q.y; red[tid][5] = q.z;
            red[tid][6] = px * q.x;  red[tid][7] = px * q.y;  red[tid][8] = px * q.z;
            red[tid][9] = py * q.x;  red[tid][10] = py * q.y; red[tid][11] = py * q.z;
            red[tid][12] = pz * q.x; red[tid][13] = pz * q.y; red[tid][14] = pz * q.z;
            red[tid][15] = dist;
        }
        __syncthreads();
        if (tid < 16) {
            float s = 0.f;
#pragma unroll
            for (int r = 0; r < 8; ++r) s += red[r][tid];
            // striped RMW: 32 slots/batch, 32 blocks each (R6-measured cheap)
            atomicAdd(&acc[(((size_t)step * 2 + b) * NSLOT + (bid & (NSLOT - 1))) * 16 + tid], s);
        }

        grid_barrier(ctrs + step * CTR_STRIDE, bid);

        // gather 32 slots x 32 components (plain loads; region first touched
        // post-barrier, atomics bypassed L2 -> no staleness; R8-proven)
        if (tid < 32) {
            int bb = tid >> 4, c = tid & 15;
            const float* base = acc + (((size_t)step * 2 + bb) * NSLOT) * 16 + c;
            float s = 0.f;
#pragma unroll
            for (int sl = 0; sl < NSLOT; ++sl) s += base[sl * 16];
            asum[bb][c] = s;
        }
        __syncthreads();

        float a[16];
        float errnew = 0.f;
        if (tid < 2) {
            for (int i = 0; i < 16; ++i) a[i] = asum[tid][i];
            errnew = a[15] * (1.f / NPTS);
            convs[tid] = (fabsf(errnew - st[tid][12]) < ICP_TOL) ? 1.f : 0.f;
        }
        __syncthreads();
        bool done_new = (convs[0] != 0.f) && (convs[1] != 0.f);

        if (tid < 2 && !done_new) {
            const float inv_n = 1.f / NPTS;
            float pmx = a[0] * inv_n, pmy = a[1] * inv_n, pmz = a[2] * inv_n;
            float qmx = a[3] * inv_n, qmy = a[4] * inv_n, qmz = a[5] * inv_n;
            float H[3][3];
            for (int i = 0; i < 3; ++i)
                for (int j = 0; j < 3; ++j)
                    H[i][j] = a[6 + 3 * i + j] - a[i] * a[3 + j] * inv_n;

            float Sxx = H[0][0], Sxy = H[0][1], Sxz = H[0][2];
            float Syx = H[1][0], Syy = H[1][1], Syz = H[1][2];
            float Szx = H[2][0], Szy = H[2][1], Szz = H[2][2];

            float A[4][4];
            A[0][0] = Sxx + Syy + Szz;
            A[0][1] = Syz - Szy;
            A[0][2] = Szx - Sxz;
            A[0][3] = Sxy - Syx;
            A[1][1] = Sxx - Syy - Szz;
            A[1][2] = Sxy + Syx;
            A[1][3] = Szx + Sxz;
            A[2][2] = -Sxx + Syy - Szz;
            A[2][3] = Syz + Szy;
            A[3][3] = -Sxx - Syy + Szz;
            A[1][0] = A[0][1]; A[2][0] = A[0][2]; A[3][0] = A[0][3];
            A[2][1] = A[1][2]; A[3][1] = A[1][3]; A[3][2] = A[2][3];

            float V[4][4];
            jacobi4(A, V);
            int bi = 0;
            float bv = A[0][0];
            for (int i = 1; i < 4; ++i)
                if (A[i][i] > bv) { bv = A[i][i]; bi = i; }
            float qw = V[0][bi], qx = V[1][bi], qy = V[2][bi], qz = V[3][bi];
            float nr = frsq(qw * qw + qx * qx + qy * qy + qz * qz);
            qw *= nr; qx *= nr; qy *= nr; qz *= nr;

            float R00n = 1.f - 2.f * (qy * qy + qz * qz);
            float R01n = 2.f * (qx * qy - qw * qz);
            float R02n = 2.f * (qx * qz + qw * qy);
            float R10n = 2.f * (qx * qy + qw * qz);
            float R11n = 1.f - 2.f * (qx * qx + qz * qz);
            float R12n = 2.f * (qy * qz - qw * qx);
            float R20n = 2.f * (qx * qz - qw * qy);
            float R21n = 2.f * (qy * qz + qw * qx);
            float R22n = 1.f - 2.f * (qx * qx + qy * qy);

            float tx = qmx - (R00n * pmx + R01n * pmy + R02n * pmz);
            float ty = qmy - (R10n * pmx + R11n * pmy + R12n * pmz);
            float tz = qmz - (R20n * pmx + R21n * pmy + R22n * pmz);

            float C00 = st[tid][0], C01 = st[tid][1], C02 = st[tid][2];
            float C10 = st[tid][3], C11 = st[tid][4], C12 = st[tid][5];
            float C20 = st[tid][6], C21 = st[tid][7], C22 = st[tid][8];
            float T0 = st[tid][9], T1 = st[tid][10], T2 = st[tid][11];

            st[tid][0] = R00n * C00 + R01n * C10 + R02n * C20;
            st[tid][1] = R00n * C01 + R01n * C11 + R02n * C21;
            st[tid][2] = R00n * C02 + R01n * C12 + R02n * C22;
            st[tid][3] = R10n * C00 + R11n * C10 + R12n * C20;
            st[tid][4] = R10n * C01 + R11n * C11 + R12n * C21;
            st[tid][5] = R10n * C02 + R11n * C12 + R12n * C22;
            st[tid][6] = R20n * C00 + R21n * C10 + R22n * C20;
            st[tid][7] = R20n * C01 + R21n * C11 + R22n * C21;
            st[tid][8] = R20n * C02 + R21n * C12 + R22n * C22;
            st[tid][9]  = R00n * T0 + R01n * T1 + R02n * T2 + tx;
            st[tid][10] = R10n * T0 + R11n * T1 + R12n * T2 + ty;
            st[tid][11] = R20n * T0 + R21n * T1 + R22n * T2 + tz;
            st[tid][12] = errnew;
        }
        __syncthreads();
        if (done_new) break;
    }

    if (bid == 0 && tid < 2) {
        float r00 = st[tid][0], r01 = st[tid][1], r02 = st[tid][2];
        float r10 = st[tid][3], r11 = st[tid][4], r12 = st[tid][5];
        float r20 = st[tid][6], r21 = st[tid][7], r22 = st[tid][8];
        float qw = 0.5f * sqrtf(fmaxf(1.f + r00 + r11 + r22, 1e-12f));
        float qx = 0.5f * sqrtf(fmaxf(1.f + r00 - r11 - r22, 1e-12f));
        float qy = 0.5f * sqrtf(fmaxf(1.f - r00 + r11 - r22, 1e-12f));
        float qz = 0.5f * sqrtf(fmaxf(1.f - r00 - r11 + r22, 1e-12f));
        qx = (r21 - r12 >= 0.f) ? qx : -qx;
        qy = (r02 - r20 >= 0.f) ? qy : -qy;
        qz = (r10 - r01 >= 0.f) ? qz : -qz;
        out[tid * 7 + 0] = st[tid][9];
        out[tid * 7 + 1] = st[tid][10];
        out[tid * 7 + 2] = st[tid][11];
        out[tid * 7 + 3] = qx;
        out[tid * 7 + 4] = qy;
        out[tid * 7 + 5] = qz;
        out[tid * 7 + 6] = qw;
    }
}

extern "C" void kernel_launch(void* const* d_in, const int* in_sizes, int n_in,
                              void* d_out, int out_size, void* d_ws, size_t ws_size,
                              hipStream_t stream) {
    const float* psrc = (const float*)d_in[0];
    const float* ptgt = (const float*)d_in[1];
    float* out = (float*)d_out;
    float* ws = (float*)d_ws;

    init_kernel<<<32, 256, 0, stream>>>(ptgt, ws);
    icp_main<<<NBLK, 256, 0, stream>>>(psrc, ws, out);
}

// Round 12
// 173.314 us; speedup vs baseline: 4.7759x; 4.7759x over previous
//
#include <hip/hip_runtime.h>
#include <math.h>

#define NPTS 4096
#define MPTS 4096
#define NSTEPS 8
#define ICP_TOL 1e-6f
#define NBLK 512    // 2 blocks/CU @ launch_bounds(256,2): proven resident, no spill (R5-R8)
#define NSUB 32     // arrival sub-counters, 16 blocks each

// ws layout (floats):
//   ptgt4 : [0, 32768)         interleaved {x,y,z,0.5*|t|^2}, 2*4096 targets
//   acc   : [32768, 98304)     [step][block(512)][16] per-block partials (atomic stores)
//   ctrs  : words at 98304, 1536/step: subs at c*16 (c<32), master at 512,
//           flags at 1024+f*16 (f<32); value 0=wait, 1=continue, 2=done
//   stpub : floats at 110592, 32/step: [step][batch][16] published R(9)+t(3)
#define ACC_OFF 32768
#define CTR_OFF 98304
#define CTR_STRIDE 1536
#define STPUB_OFF 110592

__global__ void init_kernel(const float* __restrict__ ptgt, float* __restrict__ ws) {
    float* ptgt4 = ws;
    unsigned* ctrs = (unsigned*)(ws + CTR_OFF);
    int gid = blockIdx.x * 256 + threadIdx.x;   // 8192 threads
    if (gid < 2 * MPTS) {
        float x = ptgt[3 * gid + 0];
        float y = ptgt[3 * gid + 1];
        float z = ptgt[3 * gid + 2];
        float4 v;
        v.x = x; v.y = y; v.z = z;
        v.w = 0.5f * (x * x + y * y + z * z);
        ((float4*)ptgt4)[gid] = v;
    }
    for (int i = gid; i < NSTEPS * CTR_STRIDE; i += 8192) ctrs[i] = 0u;
}

__device__ __forceinline__ float frcp(float x) {
#if __has_builtin(__builtin_amdgcn_rcpf)
    return __builtin_amdgcn_rcpf(x);
#else
    return 1.f / x;
#endif
}
__device__ __forceinline__ float frsq(float x) {
#if __has_builtin(__builtin_amdgcn_rsqf)
    return __builtin_amdgcn_rsqf(x);
#else
    return 1.f / sqrtf(x);
#endif
}

#define DET3(a,b,c,d,e,f,g,h,i) \
    ((a)*((e)*(i)-(f)*(h)) - (b)*((d)*(i)-(f)*(g)) + (c)*((d)*(h)-(e)*(g)))

// Max-eigenpair of symmetric 4x4 via Newton on the characteristic quartic
// (monotone from Gershgorin upper bound) + cofactor-row eigenvector.
// Serial chain ~1200 cyc vs ~4800 for 5-sweep Jacobi. All constant indices.
__device__ __forceinline__ void horn_quat(const float N[4][4], float q[4]) {
    float s = 1e-30f;
#pragma unroll
    for (int i = 0; i < 4; ++i)
#pragma unroll
        for (int j = 0; j < 4; ++j) s = fmaxf(s, fabsf(N[i][j]));
    float inv = frcp(s);
    float A[4][4], B[4][4];
#pragma unroll
    for (int i = 0; i < 4; ++i)
#pragma unroll
        for (int j = 0; j < 4; ++j) A[i][j] = N[i][j] * inv;
#pragma unroll
    for (int i = 0; i < 4; ++i)
#pragma unroll
        for (int j = i; j < 4; ++j) {
            float v = A[i][0]*A[0][j] + A[i][1]*A[1][j] + A[i][2]*A[2][j] + A[i][3]*A[3][j];
            B[i][j] = v; B[j][i] = v;
        }
    float p1 = A[0][0]+A[1][1]+A[2][2]+A[3][3];
    float p2 = B[0][0]+B[1][1]+B[2][2]+B[3][3];
    float p3 = 0.f, p4 = 0.f;
#pragma unroll
    for (int i = 0; i < 4; ++i)
#pragma unroll
        for (int j = 0; j < 4; ++j) { p3 += A[i][j]*B[i][j]; p4 += B[i][j]*B[i][j]; }
    float e1 = p1;
    float e2 = 0.5f*(e1*p1 - p2);
    float e3 = (e2*p1 - e1*p2 + p3)*(1.f/3.f);
    float e4 = 0.25f*(e3*p1 - e2*p2 + e1*p3 - p4);
    // Gershgorin upper bound on lambda_max
    float lam = -3e38f;
#pragma unroll
    for (int i = 0; i < 4; ++i) {
        float r = A[i][i];
#pragma unroll
        for (int j = 0; j < 4; ++j) if (j != i) r += fabsf(A[i][j]);
        lam = fmaxf(lam, r);
    }
#pragma unroll
    for (int it = 0; it < 12; ++it) {
        float pv = (((lam - e1)*lam + e2)*lam - e3)*lam + e4;
        float dv = ((4.f*lam - 3.f*e1)*lam + 2.f*e2)*lam - e3;
        lam -= pv * frcp(dv);
    }
    float M[4][4];
#pragma unroll
    for (int i = 0; i < 4; ++i)
#pragma unroll
        for (int j = 0; j < 4; ++j) M[i][j] = A[i][j] - ((i == j) ? lam : 0.f);
    float C0 = DET3(M[1][1],M[1][2],M[1][3], M[2][1],M[2][2],M[2][3], M[3][1],M[3][2],M[3][3]);
    float C1 = DET3(M[0][0],M[0][2],M[0][3], M[2][0],M[2][2],M[2][3], M[3][0],M[3][2],M[3][3]);
    float C2 = DET3(M[0][0],M[0][1],M[0][3], M[1][0],M[1][1],M[1][3], M[3][0],M[3][1],M[3][3]);
    float C3 = DET3(M[0][0],M[0][1],M[0][2], M[1][0],M[1][1],M[1][2], M[2][0],M[2][1],M[2][2]);
    int is = 0; float cb = fabsf(C0);
    if (fabsf(C1) > cb) { cb = fabsf(C1); is = 1; }
    if (fabsf(C2) > cb) { cb = fabsf(C2); is = 2; }
    if (fabsf(C3) > cb) { cb = fabsf(C3); is = 3; }
    float v0, v1, v2, v3;
#define ROWCOF(a,b,c) { \
    v0 =  DET3(M[a][1],M[a][2],M[a][3], M[b][1],M[b][2],M[b][3], M[c][1],M[c][2],M[c][3]); \
    v1 = -DET3(M[a][0],M[a][2],M[a][3], M[b][0],M[b][2],M[b][3], M[c][0],M[c][2],M[c][3]); \
    v2 =  DET3(M[a][0],M[a][1],M[a][3], M[b][0],M[b][1],M[b][3], M[c][0],M[c][1],M[c][3]); \
    v3 = -DET3(M[a][0],M[a][1],M[a][2], M[b][0],M[b][1],M[b][2], M[c][0],M[c][1],M[c][2]); }
    if (is == 0)      ROWCOF(1,2,3)
    else if (is == 1) ROWCOF(0,2,3)
    else if (is == 2) ROWCOF(0,1,3)
    else              ROWCOF(0,1,2)
#undef ROWCOF
    float nr = frsq(v0*v0 + v1*v1 + v2*v2 + v3*v3);
    q[0] = v0*nr; q[1] = v1*nr; q[2] = v2*nr; q[3] = v3*nr;
}

#define FOR16(OP) OP(0) OP(1) OP(2) OP(3) OP(4) OP(5) OP(6) OP(7) \
                  OP(8) OP(9) OP(10) OP(11) OP(12) OP(13) OP(14) OP(15)

// 512 blocks x 256 threads, persistent (2 blocks/CU). Per step: NN (16 pts,
// named scalars) -> per-block private atomic stores -> arrival RMW chain ->
// MASTER (block 0) gathers 512x16, solves Horn via Newton-quartic, publishes
// R,t (atomic stores) + striped flags (1=continue,2=done); others poll their
// flag (s_sleep backoff) and read R,t. Fence-free pattern proven R5-R8:
// __syncthreads drains vmcnt(0) before the next global op in program order.
__global__ __launch_bounds__(256, 2) void icp_main(
    const float* __restrict__ psrc, float* __restrict__ ws,
    float* __restrict__ out) {

    float* ptgt4 = ws;
    float* acc = ws + ACC_OFF;
    unsigned* ctrs = (unsigned*)(ws + CTR_OFF);
    float* stpub = ws + STPUB_OFF;

    __shared__ float st[2][13];     // per batch: Rcum(9), tcum(3), err(1)
    __shared__ unsigned keys[4][16];
    __shared__ float red[16][16];
    __shared__ float gred[16][16];  // master gather partials [group][comp]
    __shared__ float asum[2][16];
    __shared__ int contflag;        // 1=continue, 2=done

    const int tid = threadIdx.x;
    const int bid = blockIdx.x;
    const int b = bid >> 8;             // batch (256 blocks each)
    const int n0 = (bid & 255) * 16;    // this block's 16 source points

    if (tid < 2) {
        st[tid][0] = 1.f; st[tid][1] = 0.f; st[tid][2] = 0.f;
        st[tid][3] = 0.f; st[tid][4] = 1.f; st[tid][5] = 0.f;
        st[tid][6] = 0.f; st[tid][7] = 0.f; st[tid][8] = 1.f;
        st[tid][9] = 0.f; st[tid][10] = 0.f; st[tid][11] = 0.f;
        st[tid][12] = 0.f;
    }
    __syncthreads();

    const int w = tid >> 6, lane = tid & 63;
    const int m0 = w * 1024 + lane;
    const float4* tpb = (const float4*)ptgt4 + ((size_t)b * MPTS + m0);
    const float* ps = psrc + ((size_t)b * NPTS + n0) * 3;

    for (int step = 0; step < NSTEPS; ++step) {
        float R00 = st[b][0], R01 = st[b][1], R02 = st[b][2];
        float R10 = st[b][3], R11 = st[b][4], R12 = st[b][5];
        float R20 = st[b][6], R21 = st[b][7], R22 = st[b][8];
        float t0 = st[b][9], t1 = st[b][10], t2 = st[b][11];

#define DECLP(i) float px##i, py##i, pz##i;
        FOR16(DECLP)
#undef DECLP
#define LOADP(i) { float x = ps[3*(i)], y = ps[3*(i)+1], z = ps[3*(i)+2]; \
        px##i = fmaf(R00, x, fmaf(R01, y, fmaf(R02, z, t0))); \
        py##i = fmaf(R10, x, fmaf(R11, y, fmaf(R12, z, t1))); \
        pz##i = fmaf(R20, x, fmaf(R21, y, fmaf(R22, z, t2))); }
        FOR16(LOADP)
#undef LOADP

        // s = p.t - |t|^2/2; argmax s == argmin dist (strict > keeps first max)
#define DECLB(i) float bs##i = -3.0e38f; int ix##i = m0;
        FOR16(DECLB)
#undef DECLB

        float4 tc0 = tpb[0];
        float4 tc1 = tpb[64];
        int mreg = m0;
#pragma unroll
        for (int k = 0; k < 16; ++k) {
            float4 tnx = tpb[((k + 2) & 15) * 64];  // wraps harmlessly
            float tx = tc0.x, ty = tc0.y, tz = tc0.z, htn = tc0.w;
#define PAIR(i) { float s = fmaf(px##i, tx, fmaf(py##i, ty, fmaf(pz##i, tz, -htn))); \
            if (s > bs##i) { bs##i = s; ix##i = mreg; } }
            FOR16(PAIR)
#undef PAIR
            mreg += 64;
            tc0 = tc1;
            tc1 = tnx;
        }

        // wave argmax via order-preserving packed key: score hi-20 | (4095-m)
#define REDKEY(i) { unsigned ub = __float_as_uint(bs##i); \
        unsigned u = ((int)ub >= 0) ? (ub | 0x80000000u) : ~ub; \
        unsigned key = (u & 0xFFFFF000u) | (4095u - (unsigned)ix##i); \
        for (int off = 32; off; off >>= 1) { \
            unsigned o = (unsigned)__shfl_xor((int)key, off); \
            key = key > o ? key : o; } \
        if (lane == 0) keys[w][i] = key; }
        FOR16(REDKEY)
#undef REDKEY
        __syncthreads();

        if (tid < 16) {
            unsigned key = keys[0][tid];
            unsigned k1 = keys[1][tid], k2 = keys[2][tid], k3 = keys[3][tid];
            key = key > k1 ? key : k1;
            key = key > k2 ? key : k2;
            key = key > k3 ? key : k3;
            int m = 4095 - (int)(key & 0xFFFu);
            float4 qq = ((const float4*)ptgt4)[(size_t)b * MPTS + m];
            const float* pp = psrc + ((size_t)b * NPTS + n0 + tid) * 3;
            float x = pp[0], y = pp[1], z = pp[2];
            float px = fmaf(R00, x, fmaf(R01, y, fmaf(R02, z, t0)));
            float py = fmaf(R10, x, fmaf(R11, y, fmaf(R12, z, t1)));
            float pz = fmaf(R20, x, fmaf(R21, y, fmaf(R22, z, t2)));
            float dx = px - qq.x, dy = py - qq.y, dz = pz - qq.z;
            float dist = sqrtf(dx * dx + dy * dy + dz * dz);
            red[tid][0] = px; red[tid][1] = py; red[tid][2] = pz;
            red[tid][3] = qq.x; red[tid][4] = qq.y; red[tid][5] = qq.z;
            red[tid][6] = px * qq.x;  red[tid][7] = px * qq.y;  red[tid][8] = px * qq.z;
            red[tid][9] = py * qq.x;  red[tid][10] = py * qq.y; red[tid][11] = py * qq.z;
            red[tid][12] = pz * qq.x; red[tid][13] = pz * qq.y; red[tid][14] = pz * qq.z;
            red[tid][15] = dist;
        }
        __syncthreads();
        if (tid < 16) {
            float s = 0.f;
#pragma unroll
            for (int r = 0; r < 16; ++r) s += red[r][tid];
            __hip_atomic_store(&acc[((size_t)step * NBLK + bid) * 16 + tid], s,
                               __ATOMIC_RELAXED, __HIP_MEMORY_SCOPE_AGENT);
        }

        // ---- arrival (all blocks), then master/worker split ----
        unsigned* stepc = ctrs + step * CTR_STRIDE;
        __syncthreads();   // drains the acc stores before arrival RMW
        if (tid == 0) {
            unsigned* sub = stepc + (bid & (NSUB - 1)) * 16;
            unsigned old = __hip_atomic_fetch_add(sub, 1u, __ATOMIC_RELAXED,
                                                  __HIP_MEMORY_SCOPE_AGENT);
            if (old == (unsigned)(NBLK / NSUB) - 1u)
                __hip_atomic_fetch_add(stepc + 512, 1u, __ATOMIC_RELAXED,
                                       __HIP_MEMORY_SCOPE_AGENT);
        }

        if (bid == 0) {
            if (tid == 0) {
                while (__hip_atomic_load(stepc + 512, __ATOMIC_RELAXED,
                                         __HIP_MEMORY_SCOPE_AGENT) < (unsigned)NSUB) {
                    __builtin_amdgcn_s_sleep(1);
                }
            }
            __syncthreads();
            // gather 512 slots x 16 comps with plain loads (fresh region:
            // first touch this kernel; atomic stores bypassed L2 -> L3 serves
            // correct data; proven by R8's identical pattern)
            {
                const float* accs = acc + (size_t)step * NBLK * 16;
                int c = tid & 15, g = tid >> 4;       // 16 groups x 32 slots
                float ssum = 0.f;
#pragma unroll
                for (int i = 0; i < 32; ++i)
                    ssum += accs[(size_t)(g * 32 + i) * 16 + c];
                gred[g][c] = ssum;
            }
            __syncthreads();
            if (tid < 32) {
                int bb = tid >> 4, c = tid & 15;
                float s = 0.f;
#pragma unroll
                for (int g = 0; g < 8; ++g) s += gred[bb * 8 + g][c];
                asum[bb][c] = s;
            }
            __syncthreads();
            if (tid == 0) {
                float err0 = asum[0][15] * (1.f / NPTS);
                float err1 = asum[1][15] * (1.f / NPTS);
                bool conv = (fabsf(err0 - st[0][12]) < ICP_TOL) &&
                            (fabsf(err1 - st[1][12]) < ICP_TOL);
                contflag = conv ? 2 : 1;
            }
            __syncthreads();
            if (contflag == 1 && tid < 2) {
                float a[16];
                for (int i = 0; i < 16; ++i) a[i] = asum[tid][i];
                const float inv_n = 1.f / NPTS;
                float pmx = a[0]*inv_n, pmy = a[1]*inv_n, pmz = a[2]*inv_n;
                float qmx = a[3]*inv_n, qmy = a[4]*inv_n, qmz = a[5]*inv_n;
                float H[3][3];
                for (int i = 0; i < 3; ++i)
                    for (int j = 0; j < 3; ++j)
                        H[i][j] = a[6 + 3*i + j] - a[i]*a[3 + j]*inv_n;
                float Sxx=H[0][0], Sxy=H[0][1], Sxz=H[0][2];
                float Syx=H[1][0], Syy=H[1][1], Syz=H[1][2];
                float Szx=H[2][0], Szy=H[2][1], Szz=H[2][2];
                float Nm[4][4];
                Nm[0][0] = Sxx+Syy+Szz; Nm[0][1] = Syz-Szy;
                Nm[0][2] = Szx-Sxz;     Nm[0][3] = Sxy-Syx;
                Nm[1][1] = Sxx-Syy-Szz; Nm[1][2] = Sxy+Syx; Nm[1][3] = Szx+Sxz;
                Nm[2][2] = -Sxx+Syy-Szz; Nm[2][3] = Syz+Szy;
                Nm[3][3] = -Sxx-Syy+Szz;
                Nm[1][0]=Nm[0][1]; Nm[2][0]=Nm[0][2]; Nm[3][0]=Nm[0][3];
                Nm[2][1]=Nm[1][2]; Nm[3][1]=Nm[1][3]; Nm[3][2]=Nm[2][3];
                float qv[4];
                horn_quat(Nm, qv);
                float qw = qv[0], qx = qv[1], qy = qv[2], qz = qv[3];
                float R00n = 1.f - 2.f*(qy*qy + qz*qz);
                float R01n = 2.f*(qx*qy - qw*qz);
                float R02n = 2.f*(qx*qz + qw*qy);
                float R10n = 2.f*(qx*qy + qw*qz);
                float R11n = 1.f - 2.f*(qx*qx + qz*qz);
                float R12n = 2.f*(qy*qz - qw*qx);
                float R20n = 2.f*(qx*qz - qw*qy);
                float R21n = 2.f*(qy*qz + qw*qx);
                float R22n = 1.f - 2.f*(qx*qx + qy*qy);
                float tx = qmx - (R00n*pmx + R01n*pmy + R02n*pmz);
                float ty = qmy - (R10n*pmx + R11n*pmy + R12n*pmz);
                float tz = qmz - (R20n*pmx + R21n*pmy + R22n*pmz);
                float C00=st[tid][0], C01=st[tid][1], C02=st[tid][2];
                float C10=st[tid][3], C11=st[tid][4], C12=st[tid][5];
                float C20=st[tid][6], C21=st[tid][7], C22=st[tid][8];
                float T0=st[tid][9], T1=st[tid][10], T2=st[tid][11];
                float ns[12];
                ns[0] = R00n*C00 + R01n*C10 + R02n*C20;
                ns[1] = R00n*C01 + R01n*C11 + R02n*C21;
                ns[2] = R00n*C02 + R01n*C12 + R02n*C22;
                ns[3] = R10n*C00 + R11n*C10 + R12n*C20;
                ns[4] = R10n*C01 + R11n*C11 + R12n*C21;
                ns[5] = R10n*C02 + R11n*C12 + R12n*C22;
                ns[6] = R20n*C00 + R21n*C10 + R22n*C20;
                ns[7] = R20n*C01 + R21n*C11 + R22n*C21;
                ns[8] = R20n*C02 + R21n*C12 + R22n*C22;
                ns[9]  = R00n*T0 + R01n*T1 + R02n*T2 + tx;
                ns[10] = R10n*T0 + R11n*T1 + R12n*T2 + ty;
                ns[11] = R20n*T0 + R21n*T1 + R22n*T2 + tz;
                for (int i = 0; i < 12; ++i) {
                    st[tid][i] = ns[i];
                    __hip_atomic_store(&stpub[step*32 + tid*16 + i], ns[i],
                                       __ATOMIC_RELAXED, __HIP_MEMORY_SCOPE_AGENT);
                }
                st[tid][12] = asum[tid][15] * (1.f / NPTS);   // errnew (was err0/err1)
            }
            __syncthreads();   // drains stpub stores before flag release
            if (tid == 0) {
                unsigned fv = (unsigned)contflag;
#pragma unroll
                for (int f = 0; f < 32; ++f)
                    __hip_atomic_store(stepc + 1024 + f*16, fv,
                                       __ATOMIC_RELAXED, __HIP_MEMORY_SCOPE_AGENT);
            }
            __syncthreads();
        } else {
            if (tid == 0) {
                unsigned* myflag = stepc + 1024 + (bid & 31) * 16;
                unsigned fv;
                while ((fv = __hip_atomic_load(myflag, __ATOMIC_RELAXED,
                                               __HIP_MEMORY_SCOPE_AGENT)) == 0u) {
                    __builtin_amdgcn_s_sleep(2);
                }
                contflag = (int)fv;
                if (fv == 1u) {
                    for (int i = 0; i < 12; ++i)
                        st[b][i] = __hip_atomic_load(&stpub[step*32 + b*16 + i],
                                                     __ATOMIC_RELAXED,
                                                     __HIP_MEMORY_SCOPE_AGENT);
                }
            }
            __syncthreads();
        }
        if (contflag == 2) break;   // uniform across the grid
    }

    if (bid == 0 && tid < 2) {
        float r00 = st[tid][0], r01 = st[tid][1], r02 = st[tid][2];
        float r10 = st[tid][3], r11 = st[tid][4], r12 = st[tid][5];
        float r20 = st[tid][6], r21 = st[tid][7], r22 = st[tid][8];
        float qw = 0.5f * sqrtf(fmaxf(1.f + r00 + r11 + r22, 1e-12f));
        float qx = 0.5f * sqrtf(fmaxf(1.f + r00 - r11 - r22, 1e-12f));
        float qy = 0.5f * sqrtf(fmaxf(1.f - r00 + r11 - r22, 1e-12f));
        float qz = 0.5f * sqrtf(fmaxf(1.f - r00 - r11 + r22, 1e-12f));
        qx = (r21 - r12 >= 0.f) ? qx : -qx;
        qy = (r02 - r20 >= 0.f) ? qy : -qy;
        qz = (r10 - r01 >= 0.f) ? qz : -qz;
        out[tid * 7 + 0] = st[tid][9];
        out[tid * 7 + 1] = st[tid][10];
        out[tid * 7 + 2] = st[tid][11];
        out[tid * 7 + 3] = qx;
        out[tid * 7 + 4] = qy;
        out[tid * 7 + 5] = qz;
        out[tid * 7 + 6] = qw;
    }
}

extern "C" void kernel_launch(void* const* d_in, const int* in_sizes, int n_in,
                              void* d_out, int out_size, void* d_ws, size_t ws_size,
                              hipStream_t stream) {
    const float* psrc = (const float*)d_in[0];
    const float* ptgt = (const float*)d_in[1];
    float* out = (float*)d_out;
    float* ws = (float*)d_ws;

    init_kernel<<<32, 256, 0, stream>>>(ptgt, ws);
    icp_main<<<NBLK, 256, 0, stream>>>(psrc, ws, out);
}